// Round 5
// baseline (244.548 us; speedup 1.0000x reference)
//
#include <hip/hip_runtime.h>
#include <cstddef>

constexpr int Bc = 2, Sc = 2048, Hc = 16, Dc = 64, HIDc = 1024;
#define NEG_INF -10000.0f
#define LOG2E 1.44269504088896340736f

typedef _Float16 half8  __attribute__((ext_vector_type(8)));  // K=32 MFMA A/B frag
typedef _Float16 half4  __attribute__((ext_vector_type(4)));  // K=16 MFMA A/B frag
typedef float   floatx4 __attribute__((ext_vector_type(4)));  // MFMA C/D frag

// direct HBM -> LDS, 16B per lane, lane i lands at ldsbase + i*16
__device__ __forceinline__ void gload_lds16(const void* g, void* l) {
    __builtin_amdgcn_global_load_lds(
        (const __attribute__((address_space(1))) unsigned int*)g,
        (__attribute__((address_space(3))) unsigned int*)l, 16, 0, 0);
}

// ---------------------------------------------------------------------------
// cvt_x: x fp32 [4096][1024] -> f16 same layout. 8 elements/thread.
// ---------------------------------------------------------------------------
__global__ __launch_bounds__(256) void cvt_x_kernel(const float* __restrict__ x,
                                                    _Float16* __restrict__ xh) {
    int i = (blockIdx.x * 256 + threadIdx.x) * 8;
    float4 a = *(const float4*)(x + i);
    float4 b = *(const float4*)(x + i + 4);
    half8 h;
    h[0] = (_Float16)a.x; h[1] = (_Float16)a.y; h[2] = (_Float16)a.z; h[3] = (_Float16)a.w;
    h[4] = (_Float16)b.x; h[5] = (_Float16)b.y; h[6] = (_Float16)b.z; h[7] = (_Float16)b.w;
    *(half8*)(xh + i) = h;
}

// ---------------------------------------------------------------------------
// cvt_w: W fp32 [k][n] -> Wt f16 [n][k] (transposed), per z in {q,k,v}.
// ---------------------------------------------------------------------------
__global__ __launch_bounds__(256) void cvt_w_kernel(const float* __restrict__ Wq,
                                                    const float* __restrict__ Wk,
                                                    const float* __restrict__ Wv,
                                                    _Float16* __restrict__ Wt) {
    const float* W = (blockIdx.z == 0) ? Wq : (blockIdx.z == 1) ? Wk : Wv;
    _Float16* out = Wt + (size_t)blockIdx.z * HIDc * HIDc;
    __shared__ _Float16 T[64][65];
    const int t = threadIdx.x;
    const int kb = blockIdx.x * 64, nb = blockIdx.y * 64;
    const int r = t >> 2, c4 = (t & 3) * 16;
    #pragma unroll
    for (int i = 0; i < 16; i += 4) {
        float4 a = *(const float4*)(W + (size_t)(kb + r) * HIDc + nb + c4 + i);
        T[c4 + i + 0][r] = (_Float16)a.x;
        T[c4 + i + 1][r] = (_Float16)a.y;
        T[c4 + i + 2][r] = (_Float16)a.z;
        T[c4 + i + 3][r] = (_Float16)a.w;
    }
    __syncthreads();
    const int n = t >> 2, k4 = (t & 3) * 16;
    half8 o0, o1;
    #pragma unroll
    for (int j = 0; j < 8; ++j) { o0[j] = T[n][k4 + j]; o1[j] = T[n][k4 + 8 + j]; }
    *(half8*)(out + (size_t)(nb + n) * HIDc + kb + k4)     = o0;
    *(half8*)(out + (size_t)(nb + n) * HIDc + kb + k4 + 8) = o1;
}

// ---------------------------------------------------------------------------
// proj R15: byte-identical to R12 (m97-structure, passing).
// ---------------------------------------------------------------------------
__global__ __launch_bounds__(256, 3) void proj_kernel(
    const _Float16* __restrict__ xh, const _Float16* __restrict__ Wt,
    const float* __restrict__ bq, const float* __restrict__ bk, const float* __restrict__ bv,
    _Float16* __restrict__ qw, _Float16* __restrict__ kw, _Float16* __restrict__ vt)
{
    const int z = blockIdx.z;
    const _Float16* Wz = Wt + (size_t)z * HIDc * HIDc;
    const float* bias = (z == 0) ? bq : (z == 1) ? bk : bv;

    __shared__ __align__(16) _Float16 SM[2][2][128 * 32];

    const int t = threadIdx.x;
    const int lane = t & 63, w = t >> 6;
    const int quad = lane >> 4, l16 = lane & 15;
    const int m0 = blockIdx.y * 128, n0 = blockIdx.x * 128;
    const int wm = (w >> 1) * 64, wn = (w & 1) * 64;

    const int srl = lane >> 2;                       // row in 16-row chunk
    const int ssl = (lane & 3) ^ ((lane >> 3) & 3);  // pre-swizzled src slot

    floatx4 acc[4][4];
    #pragma unroll
    for (int mb = 0; mb < 4; ++mb)
        #pragma unroll
        for (int nb = 0; nb < 4; ++nb) acc[mb][nb] = floatx4{0.f, 0.f, 0.f, 0.f};

    auto stage = [&](int buf, int kt) {   // kt in halves
        #pragma unroll
        for (int j = 0; j < 2; ++j) {
            const int rb = (w + 4 * j) * 16;   // wave-uniform row base
            gload_lds16(xh + (size_t)(m0 + rb + srl) * HIDc + kt + ssl * 8,
                        &SM[buf][0][rb * 32]);
            gload_lds16(Wz + (size_t)(n0 + rb + srl) * HIDc + kt + ssl * 8,
                        &SM[buf][1][rb * 32]);
        }
    };

    stage(0, 0);
    __syncthreads();

    const int sA = (quad ^ ((l16 >> 1) & 3)) * 8;

    #pragma unroll 2
    for (int it = 0; it < HIDc / 32; ++it) {
        const int cur = it & 1;
        const int kn = (it + 1 < HIDc / 32) ? (it + 1) * 32 : 0;
        stage(cur ^ 1, kn);

        half8 af[4], bf[4];
        #pragma unroll
        for (int mb = 0; mb < 4; ++mb)
            af[mb] = *(const half8*)(&SM[cur][0][(wm + mb * 16 + l16) * 32 + sA]);
        #pragma unroll
        for (int nb = 0; nb < 4; ++nb)
            bf[nb] = *(const half8*)(&SM[cur][1][(wn + nb * 16 + l16) * 32 + sA]);
        #pragma unroll
        for (int mb = 0; mb < 4; ++mb)
            #pragma unroll
            for (int nb = 0; nb < 4; ++nb)
                acc[mb][nb] = __builtin_amdgcn_mfma_f32_16x16x32_f16(
                    af[mb], bf[nb], acc[mb][nb], 0, 0, 0);
        __syncthreads();
    }

    if (z == 2) {
        _Float16* T = (_Float16*)SM;     // 64 x 136 halves
        const int bI0 = m0 >> 11, m0s = m0 & (Sc - 1);
        #pragma unroll
        for (int p = 0; p < 2; ++p) {
            __syncthreads();
            if ((w & 1) == p) {
                #pragma unroll
                for (int nb = 0; nb < 4; ++nb) {
                    const int n = nb * 16 + l16;
                    const float bi = bias[n0 + p * 64 + n];
                    #pragma unroll
                    for (int mb = 0; mb < 4; ++mb) {
                        half4 h4;
                        #pragma unroll
                        for (int r = 0; r < 4; ++r)
                            h4[r] = (_Float16)(acc[mb][nb][r] + bi);
                        *(half4*)(T + n * 136 + wm + mb * 16 + quad * 4) = h4;
                    }
                }
            }
            __syncthreads();
            const int n = t >> 2;
            const int N = n0 + p * 64 + n, hh = N >> 6, d = N & 63;
            _Float16* vrow = vt + (((size_t)(bI0 * Hc + hh)) * Dc + d) * Sc + m0s;
            #pragma unroll
            for (int j = 0; j < 4; ++j) {
                const int c = (t & 3) * 32 + j * 8;
                *(uint4*)(vrow + c) = *(const uint4*)(T + n * 136 + c);
            }
        }
        return;
    }
    #pragma unroll
    for (int nb = 0; nb < 4; ++nb) {
        const int N = n0 + wn + nb * 16 + l16;
        const float bi = bias[N];
        const int h = N >> 6, d = N & 63;
        #pragma unroll
        for (int mb = 0; mb < 4; ++mb) {
            #pragma unroll
            for (int r = 0; r < 4; ++r) {
                const int M = m0 + wm + mb * 16 + quad * 4 + r;
                const int bI = M >> 11, s = M & (Sc - 1);
                const float v = acc[mb][nb][r] + bi;
                if (z == 0)
                    qw[(((size_t)(bI * Hc + h)) * Sc + s) * Dc + d] =
                        (_Float16)(v * (0.125f * LOG2E));
                else
                    kw[(((size_t)(bI * Hc + h)) * Sc + s) * Dc + d] = (_Float16)v;
            }
        }
    }
}

// ---------------------------------------------------------------------------
// attn R15: R14 with the K-staging bug fixed. 256 threads x 32 halves
// (4 x uint4) = 128 rows x 64 halves per tile — R14 only wrote 16
// halves/thread, leaving half of each LDS row uninitialized (NaN source).
// Structure: V direct-from-global (no V LDS), KVBLK=128, one barrier/tile.
// ---------------------------------------------------------------------------
__global__ __launch_bounds__(256, 2) void attn_kernel(
    const _Float16* __restrict__ qw, const _Float16* __restrict__ kw,
    const _Float16* __restrict__ vt, const int* __restrict__ mask,
    float* __restrict__ out)
{
    __shared__ __align__(16) float adder[Sc];           // 8 KB (pre-scaled log2e)
    __shared__ __align__(16) _Float16 Ks[2][128][72];   // 36.9 KB  [key][d]

    const int t = threadIdx.x;
    const int lane = t & 63, w = t >> 6;
    const int quad = lane >> 4, l16 = lane & 15;
    const int bh = blockIdx.y;
    const int bI = bh >> 4, h = bh & 15;

    const _Float16* Qp = qw + (size_t)bh * Sc * Dc;
    const _Float16* Kp = kw + (size_t)bh * Sc * Dc;
    const _Float16* Vp = vt + (size_t)bh * Dc * Sc;

    // K staging: thread t covers row t>>1 (0..127), 32-half chunk (t&1)*32,
    // via FOUR uint4s (32 halves = full coverage: 256 thr x 32 = 128 x 64)
    const int srow = t >> 1;
    const int scol = (t & 1) * 32;

    {   // mask -> additive adder in LDS, pre-scaled by log2e
        const int4* mp = (const int4*)(mask + bI * Sc);
        #pragma unroll
        for (int i = 0; i < 2; ++i) {
            int4 m4 = mp[t * 2 + i];
            int base = (t * 2 + i) * 4;
            adder[base + 0] = (1.0f - (float)m4.x) * (NEG_INF * LOG2E);
            adder[base + 1] = (1.0f - (float)m4.y) * (NEG_INF * LOG2E);
            adder[base + 2] = (1.0f - (float)m4.z) * (NEG_INF * LOG2E);
            adder[base + 3] = (1.0f - (float)m4.w) * (NEG_INF * LOG2E);
        }
    }
    // preload K tile 0 (rows 0..127) into buffer 0
    {
        const _Float16* kp = Kp + (size_t)srow * Dc + scol;
        #pragma unroll
        for (int j = 0; j < 4; ++j)
            *(uint4*)(&Ks[0][srow][scol + j * 8]) = *(const uint4*)(kp + j * 8);
    }

    const int qrow = blockIdx.x * 128 + w * 32;
    half8 aq[2][2];
    #pragma unroll
    for (int s = 0; s < 2; ++s)
        #pragma unroll
        for (int hh = 0; hh < 2; ++hh)
            aq[s][hh] = *(const half8*)(Qp + (size_t)(qrow + 16 * s + l16) * Dc
                                        + hh * 32 + quad * 8);

    floatx4 o[2][4], osum[2];
    #pragma unroll
    for (int s = 0; s < 2; ++s) {
        osum[s] = floatx4{0.f, 0.f, 0.f, 0.f};
        #pragma unroll
        for (int db = 0; db < 4; ++db) o[s][db] = floatx4{0.f, 0.f, 0.f, 0.f};
    }
    const half4 ones4 = {(_Float16)1.f, (_Float16)1.f, (_Float16)1.f, (_Float16)1.f};

    __syncthreads();   // adder + tile 0 visible

    #pragma unroll 2
    for (int it = 0; it < Sc / 128; ++it) {
        const int cur = it & 1;
        const int kt = it * 128;
        const int ktn = (it + 1 < Sc / 128) ? kt + 128 : 0;
        // stage next K tile into regs (no barrier dependency on issue)
        uint4 ks[4];
        {
            const _Float16* kp = Kp + (size_t)(ktn + srow) * Dc + scol;
            #pragma unroll
            for (int j = 0; j < 4; ++j) ks[j] = *(const uint4*)(kp + j * 8);
        }

        #pragma unroll
        for (int hb = 0; hb < 2; ++hb) {   // two 64-key halves
            const int kb0 = hb * 64;

            // V fragments straight from global (issued first; consumed after
            // QK+exp, so L1/L2 latency is hidden under the MFMA/trans chain)
            half4 vb[4][4];
            #pragma unroll
            for (int nb = 0; nb < 4; ++nb)
                #pragma unroll
                for (int db = 0; db < 4; ++db)
                    vb[nb][db] = *(const half4*)(
                        Vp + (size_t)(db * 16 + l16) * Sc + kt + kb0 + nb * 16 + quad * 4);

            // K fragments from LDS
            half8 kb[4][2];
            #pragma unroll
            for (int nb = 0; nb < 4; ++nb)
                #pragma unroll
                for (int hh = 0; hh < 2; ++hh)
                    kb[nb][hh] = *(const half8*)(
                        &Ks[cur][kb0 + nb * 16 + l16][hh * 32 + quad * 8]);

            // QK^T with adder as C-init
            floatx4 st[2][4];
            __builtin_amdgcn_s_setprio(1);
            #pragma unroll
            for (int nb = 0; nb < 4; ++nb) {
                const floatx4 adv = *(const floatx4*)(&adder[kt + kb0 + nb * 16 + quad * 4]);
                #pragma unroll
                for (int s = 0; s < 2; ++s) {
                    floatx4 x0 = __builtin_amdgcn_mfma_f32_16x16x32_f16(kb[nb][0], aq[s][0], adv, 0, 0, 0);
                    st[s][nb]  = __builtin_amdgcn_mfma_f32_16x16x32_f16(kb[nb][1], aq[s][1], x0, 0, 0, 0);
                }
            }
            __builtin_amdgcn_s_setprio(0);

            // softmax numerators: p = exp2(st)
            half4 pa[2][4];
            #pragma unroll
            for (int s = 0; s < 2; ++s)
                #pragma unroll
                for (int nb = 0; nb < 4; ++nb)
                    #pragma unroll
                    for (int r = 0; r < 4; ++r)
                        pa[s][nb][r] = (_Float16)__builtin_amdgcn_exp2f(st[s][nb][r]);

            // PV + row-sum via ones-MFMA
            __builtin_amdgcn_s_setprio(1);
            #pragma unroll
            for (int s = 0; s < 2; ++s)
                #pragma unroll
                for (int nb = 0; nb < 4; ++nb) {
                    osum[s] = __builtin_amdgcn_mfma_f32_16x16x16f16(pa[s][nb], ones4, osum[s], 0, 0, 0);
                    #pragma unroll
                    for (int db = 0; db < 4; ++db)
                        o[s][db] = __builtin_amdgcn_mfma_f32_16x16x16f16(
                            pa[s][nb], vb[nb][db], o[s][db], 0, 0, 0);
                }
            __builtin_amdgcn_s_setprio(0);
        }

        // write staged K tile, one barrier per 128 keys
        #pragma unroll
        for (int j = 0; j < 4; ++j)
            *(uint4*)(&Ks[cur ^ 1][srow][scol + j * 8]) = ks[j];
        __syncthreads();
    }

    // epilogue: osum[s][r] already holds the full row-sum for q=quad*4+r
    float* op = out + (size_t)bI * Sc * HIDc + h * Dc;
    #pragma unroll
    for (int s = 0; s < 2; ++s)
        #pragma unroll
        for (int r = 0; r < 4; ++r) {
            const float inv = __builtin_amdgcn_rcpf(osum[s][r]);
            const int q = qrow + 16 * s + quad * 4 + r;
            #pragma unroll
            for (int db = 0; db < 4; ++db)
                op[(size_t)q * HIDc + db * 16 + l16] = o[s][db][r] * inv;
        }
}

// ---------------------------------------------------------------------------
extern "C" void kernel_launch(void* const* d_in, const int* in_sizes, int n_in,
                              void* d_out, int out_size, void* d_ws, size_t ws_size,
                              hipStream_t stream) {
    const float* x    = (const float*)d_in[0];
    const int*   mask = (const int*)  d_in[1];
    const float* Wq   = (const float*)d_in[2];
    const float* bq   = (const float*)d_in[3];
    const float* Wk   = (const float*)d_in[4];
    const float* bk   = (const float*)d_in[5];
    const float* Wv   = (const float*)d_in[6];
    const float* bv   = (const float*)d_in[7];
    float* out = (float*)d_out;

    // workspace (f16): xh 8MB | Wt 6MB | qw 8MB | kw 8MB | vt 8MB = 38MB
    char* ws = (char*)d_ws;
    _Float16* xh = (_Float16*)(ws);
    _Float16* Wt = (_Float16*)(ws + (size_t)8  * 1024 * 1024);
    _Float16* qw = (_Float16*)(ws + (size_t)14 * 1024 * 1024);
    _Float16* kw = (_Float16*)(ws + (size_t)22 * 1024 * 1024);
    _Float16* vt = (_Float16*)(ws + (size_t)30 * 1024 * 1024);

    cvt_x_kernel<<<(Bc * Sc * HIDc) / (256 * 8), 256, 0, stream>>>(x, xh);
    cvt_w_kernel<<<dim3(HIDc / 64, HIDc / 64, 3), 256, 0, stream>>>(Wq, Wk, Wv, Wt);
    proj_kernel<<<dim3(HIDc / 128, (Bc * Sc) / 128, 3), 256, 0, stream>>>(
        xh, Wt, bq, bk, bv, qw, kw, vt);
    attn_kernel<<<dim3(Sc / 128, Bc * Hc), 256, 0, stream>>>(qw, kw, vt, mask, out);
}

// Round 6
// 166.101 us; speedup vs baseline: 1.4723x; 1.4723x over previous
//
#include <hip/hip_runtime.h>
#include <cstddef>

constexpr int Bc = 2, Sc = 2048, Hc = 16, Dc = 64, HIDc = 1024;
#define NEG_INF -10000.0f
#define LOG2E 1.44269504088896340736f

typedef _Float16 half8  __attribute__((ext_vector_type(8)));  // K=32 MFMA A/B frag
typedef _Float16 half4  __attribute__((ext_vector_type(4)));  // K=16 MFMA A/B frag
typedef float   floatx4 __attribute__((ext_vector_type(4)));  // MFMA C/D frag

// direct HBM -> LDS, 16B per lane, lane i lands at ldsbase + i*16
__device__ __forceinline__ void gload_lds16(const void* g, void* l) {
    __builtin_amdgcn_global_load_lds(
        (const __attribute__((address_space(1))) unsigned int*)g,
        (__attribute__((address_space(3))) unsigned int*)l, 16, 0, 0);
}

// ---------------------------------------------------------------------------
// cvt_x: x fp32 [4096][1024] -> f16 same layout. 8 elements/thread.
// ---------------------------------------------------------------------------
__global__ __launch_bounds__(256) void cvt_x_kernel(const float* __restrict__ x,
                                                    _Float16* __restrict__ xh) {
    int i = (blockIdx.x * 256 + threadIdx.x) * 8;
    float4 a = *(const float4*)(x + i);
    float4 b = *(const float4*)(x + i + 4);
    half8 h;
    h[0] = (_Float16)a.x; h[1] = (_Float16)a.y; h[2] = (_Float16)a.z; h[3] = (_Float16)a.w;
    h[4] = (_Float16)b.x; h[5] = (_Float16)b.y; h[6] = (_Float16)b.z; h[7] = (_Float16)b.w;
    *(half8*)(xh + i) = h;
}

// ---------------------------------------------------------------------------
// cvt_w: W fp32 [k][n] -> Wt f16 [n][k] (transposed), per z in {q,k,v}.
// ---------------------------------------------------------------------------
__global__ __launch_bounds__(256) void cvt_w_kernel(const float* __restrict__ Wq,
                                                    const float* __restrict__ Wk,
                                                    const float* __restrict__ Wv,
                                                    _Float16* __restrict__ Wt) {
    const float* W = (blockIdx.z == 0) ? Wq : (blockIdx.z == 1) ? Wk : Wv;
    _Float16* out = Wt + (size_t)blockIdx.z * HIDc * HIDc;
    __shared__ _Float16 T[64][65];
    const int t = threadIdx.x;
    const int kb = blockIdx.x * 64, nb = blockIdx.y * 64;
    const int r = t >> 2, c4 = (t & 3) * 16;
    #pragma unroll
    for (int i = 0; i < 16; i += 4) {
        float4 a = *(const float4*)(W + (size_t)(kb + r) * HIDc + nb + c4 + i);
        T[c4 + i + 0][r] = (_Float16)a.x;
        T[c4 + i + 1][r] = (_Float16)a.y;
        T[c4 + i + 2][r] = (_Float16)a.z;
        T[c4 + i + 3][r] = (_Float16)a.w;
    }
    __syncthreads();
    const int n = t >> 2, k4 = (t & 3) * 16;
    half8 o0, o1;
    #pragma unroll
    for (int j = 0; j < 8; ++j) { o0[j] = T[n][k4 + j]; o1[j] = T[n][k4 + 8 + j]; }
    *(half8*)(out + (size_t)(nb + n) * HIDc + kb + k4)     = o0;
    *(half8*)(out + (size_t)(nb + n) * HIDc + kb + k4 + 8) = o1;
}

// ---------------------------------------------------------------------------
// proj R16: byte-identical to R12 (m97-structure, passing).
// ---------------------------------------------------------------------------
__global__ __launch_bounds__(256, 3) void proj_kernel(
    const _Float16* __restrict__ xh, const _Float16* __restrict__ Wt,
    const float* __restrict__ bq, const float* __restrict__ bk, const float* __restrict__ bv,
    _Float16* __restrict__ qw, _Float16* __restrict__ kw, _Float16* __restrict__ vt)
{
    const int z = blockIdx.z;
    const _Float16* Wz = Wt + (size_t)z * HIDc * HIDc;
    const float* bias = (z == 0) ? bq : (z == 1) ? bk : bv;

    __shared__ __align__(16) _Float16 SM[2][2][128 * 32];

    const int t = threadIdx.x;
    const int lane = t & 63, w = t >> 6;
    const int quad = lane >> 4, l16 = lane & 15;
    const int m0 = blockIdx.y * 128, n0 = blockIdx.x * 128;
    const int wm = (w >> 1) * 64, wn = (w & 1) * 64;

    const int srl = lane >> 2;                       // row in 16-row chunk
    const int ssl = (lane & 3) ^ ((lane >> 3) & 3);  // pre-swizzled src slot

    floatx4 acc[4][4];
    #pragma unroll
    for (int mb = 0; mb < 4; ++mb)
        #pragma unroll
        for (int nb = 0; nb < 4; ++nb) acc[mb][nb] = floatx4{0.f, 0.f, 0.f, 0.f};

    auto stage = [&](int buf, int kt) {   // kt in halves
        #pragma unroll
        for (int j = 0; j < 2; ++j) {
            const int rb = (w + 4 * j) * 16;   // wave-uniform row base
            gload_lds16(xh + (size_t)(m0 + rb + srl) * HIDc + kt + ssl * 8,
                        &SM[buf][0][rb * 32]);
            gload_lds16(Wz + (size_t)(n0 + rb + srl) * HIDc + kt + ssl * 8,
                        &SM[buf][1][rb * 32]);
        }
    };

    stage(0, 0);
    __syncthreads();

    const int sA = (quad ^ ((l16 >> 1) & 3)) * 8;

    #pragma unroll 2
    for (int it = 0; it < HIDc / 32; ++it) {
        const int cur = it & 1;
        const int kn = (it + 1 < HIDc / 32) ? (it + 1) * 32 : 0;
        stage(cur ^ 1, kn);

        half8 af[4], bf[4];
        #pragma unroll
        for (int mb = 0; mb < 4; ++mb)
            af[mb] = *(const half8*)(&SM[cur][0][(wm + mb * 16 + l16) * 32 + sA]);
        #pragma unroll
        for (int nb = 0; nb < 4; ++nb)
            bf[nb] = *(const half8*)(&SM[cur][1][(wn + nb * 16 + l16) * 32 + sA]);
        #pragma unroll
        for (int mb = 0; mb < 4; ++mb)
            #pragma unroll
            for (int nb = 0; nb < 4; ++nb)
                acc[mb][nb] = __builtin_amdgcn_mfma_f32_16x16x32_f16(
                    af[mb], bf[nb], acc[mb][nb], 0, 0, 0);
        __syncthreads();
    }

    if (z == 2) {
        _Float16* T = (_Float16*)SM;     // 64 x 136 halves
        const int bI0 = m0 >> 11, m0s = m0 & (Sc - 1);
        #pragma unroll
        for (int p = 0; p < 2; ++p) {
            __syncthreads();
            if ((w & 1) == p) {
                #pragma unroll
                for (int nb = 0; nb < 4; ++nb) {
                    const int n = nb * 16 + l16;
                    const float bi = bias[n0 + p * 64 + n];
                    #pragma unroll
                    for (int mb = 0; mb < 4; ++mb) {
                        half4 h4;
                        #pragma unroll
                        for (int r = 0; r < 4; ++r)
                            h4[r] = (_Float16)(acc[mb][nb][r] + bi);
                        *(half4*)(T + n * 136 + wm + mb * 16 + quad * 4) = h4;
                    }
                }
            }
            __syncthreads();
            const int n = t >> 2;
            const int N = n0 + p * 64 + n, hh = N >> 6, d = N & 63;
            _Float16* vrow = vt + (((size_t)(bI0 * Hc + hh)) * Dc + d) * Sc + m0s;
            #pragma unroll
            for (int j = 0; j < 4; ++j) {
                const int c = (t & 3) * 32 + j * 8;
                *(uint4*)(vrow + c) = *(const uint4*)(T + n * 136 + c);
            }
        }
        return;
    }
    #pragma unroll
    for (int nb = 0; nb < 4; ++nb) {
        const int N = n0 + wn + nb * 16 + l16;
        const float bi = bias[N];
        const int h = N >> 6, d = N & 63;
        #pragma unroll
        for (int mb = 0; mb < 4; ++mb) {
            #pragma unroll
            for (int r = 0; r < 4; ++r) {
                const int M = m0 + wm + mb * 16 + quad * 4 + r;
                const int bI = M >> 11, s = M & (Sc - 1);
                const float v = acc[mb][nb][r] + bi;
                if (z == 0)
                    qw[(((size_t)(bI * Hc + h)) * Sc + s) * Dc + d] =
                        (_Float16)(v * (0.125f * LOG2E));
                else
                    kw[(((size_t)(bI * Hc + h)) * Sc + s) * Dc + d] = (_Float16)v;
            }
        }
    }
}

// ---------------------------------------------------------------------------
// attn R16: R11 structure restored (K AND V both LDS-staged, 64-key tiles,
// one barrier/tile — the R13-R15 V-from-global experiment regressed 2.4x:
// 8B/lane scatter across 16 rows = 16 cache lines per VMEM instr).
// NEW: PV uses 16x16x32 MFMA. The k-axis of PV is permutation-invariant,
// and the permuted Vs layout already delivers half8 B-frags whose 8 key
// slots equal concat(pa[s][2a], pa[s][2a+1]) — a register shufflevector.
// PV drops 32+8 x16-MFMAs -> 16+4 x32-MFMAs per iter (56 -> 36 total).
// ---------------------------------------------------------------------------
__global__ __launch_bounds__(256, 2) void attn_kernel(
    const _Float16* __restrict__ qw, const _Float16* __restrict__ kw,
    const _Float16* __restrict__ vt, const int* __restrict__ mask,
    float* __restrict__ out)
{
    __shared__ __align__(16) float adder[Sc];           // 8 KB (pre-scaled log2e)
    __shared__ __align__(16) _Float16 Ks[2][64][72];    // 18 KB  [key][d]
    __shared__ __align__(16) _Float16 Vs[2][64][72];    // 18 KB  [d][key-permuted]

    const int t = threadIdx.x;
    const int lane = t & 63, w = t >> 6;
    const int quad = lane >> 4, l16 = lane & 15;
    const int bh = blockIdx.y;
    const int bI = bh >> 4, h = bh & 15;

    const _Float16* Qp = qw + (size_t)bh * Sc * Dc;
    const _Float16* Kp = kw + (size_t)bh * Sc * Dc;
    const _Float16* Vp = vt + (size_t)bh * Dc * Sc;

    const int srow = t >> 3;            // 0..31
    const int scol = (t & 7) * 8;       // elem offset, 16 B per thread
    const int m7 = t & 7;
    const int vc0 = 32 * (m7 & 1) + 4 * (m7 >> 1);   // permuted V col base

    {   // mask -> additive adder in LDS, pre-scaled by log2e
        const int4* mp = (const int4*)(mask + bI * Sc);
        #pragma unroll
        for (int i = 0; i < 2; ++i) {
            int4 m4 = mp[t * 2 + i];
            int base = (t * 2 + i) * 4;
            adder[base + 0] = (1.0f - (float)m4.x) * (NEG_INF * LOG2E);
            adder[base + 1] = (1.0f - (float)m4.y) * (NEG_INF * LOG2E);
            adder[base + 2] = (1.0f - (float)m4.z) * (NEG_INF * LOG2E);
            adder[base + 3] = (1.0f - (float)m4.w) * (NEG_INF * LOG2E);
        }
    }
    // preload tile 0 into buffer 0 (V columns permuted)
    #pragma unroll
    for (int hf = 0; hf < 2; ++hf) {
        const int row = srow + 32 * hf;
        uint4 kv = *(const uint4*)(Kp + (size_t)row * Dc + scol);
        uint4 vv = *(const uint4*)(Vp + (size_t)row * Sc + scol);
        *(uint4*)(&Ks[0][row][scol]) = kv;
        *(uint2*)(&Vs[0][row][vc0])      = make_uint2(vv.x, vv.y);
        *(uint2*)(&Vs[0][row][vc0 + 16]) = make_uint2(vv.z, vv.w);
    }

    const int qrow = blockIdx.x * 128 + w * 32;
    half8 aq[2][2];
    #pragma unroll
    for (int s = 0; s < 2; ++s)
        #pragma unroll
        for (int hh = 0; hh < 2; ++hh)
            aq[s][hh] = *(const half8*)(Qp + (size_t)(qrow + 16 * s + l16) * Dc
                                        + hh * 32 + quad * 8);

    floatx4 o[2][4], osum[2];
    #pragma unroll
    for (int s = 0; s < 2; ++s) {
        osum[s] = floatx4{0.f, 0.f, 0.f, 0.f};
        #pragma unroll
        for (int db = 0; db < 4; ++db) o[s][db] = floatx4{0.f, 0.f, 0.f, 0.f};
    }
    const half8 ones8 = {(_Float16)1.f, (_Float16)1.f, (_Float16)1.f, (_Float16)1.f,
                         (_Float16)1.f, (_Float16)1.f, (_Float16)1.f, (_Float16)1.f};

    __syncthreads();   // adder + tile 0 visible

    #pragma unroll 2
    for (int it = 0; it < Sc / 64; ++it) {
        const int cur = it & 1;
        const int kt = it * 64;
        const int ktn = (it + 1 < Sc / 64) ? kt + 64 : 0;
        uint4 kstg[2], vstg[2];
        #pragma unroll
        for (int hf = 0; hf < 2; ++hf) {
            const int row = srow + 32 * hf;
            kstg[hf] = *(const uint4*)(Kp + (size_t)(ktn + row) * Dc + scol);
            vstg[hf] = *(const uint4*)(Vp + (size_t)row * Sc + ktn + scol);
        }

        half8 kb[4][2];   // A[m=key=l16][k=d=quad*8+j]
        #pragma unroll
        for (int nb = 0; nb < 4; ++nb)
            #pragma unroll
            for (int hh = 0; hh < 2; ++hh)
                kb[nb][hh] = *(const half8*)(&Ks[cur][nb * 16 + l16][hh * 32 + quad * 8]);

        // B-frags for PV K=32: half8 per (a, db); slot j of quad maps to key
        // kappa(quad,j) = (j>>2)*16 + quad*4 + (j&3) within the 32-key pair —
        // exactly the permuted-column layout Vs was stored in.
        half8 vb8[2][4];
        #pragma unroll
        for (int db = 0; db < 4; ++db)
            #pragma unroll
            for (int a = 0; a < 2; ++a)
                vb8[a][db] = *(const half8*)(&Vs[cur][db * 16 + l16][quad * 16 + a * 8]);

        // QK^T with adder as C-init
        floatx4 st[2][4];
        __builtin_amdgcn_s_setprio(1);
        #pragma unroll
        for (int nb = 0; nb < 4; ++nb) {
            const floatx4 adv = *(const floatx4*)(&adder[kt + nb * 16 + quad * 4]);
            #pragma unroll
            for (int s = 0; s < 2; ++s) {
                floatx4 x0 = __builtin_amdgcn_mfma_f32_16x16x32_f16(kb[nb][0], aq[s][0], adv, 0, 0, 0);
                st[s][nb]  = __builtin_amdgcn_mfma_f32_16x16x32_f16(kb[nb][1], aq[s][1], x0, 0, 0, 0);
            }
        }
        __builtin_amdgcn_s_setprio(0);

        // softmax numerators: p = exp2(st)
        half4 pa[2][4];
        #pragma unroll
        for (int s = 0; s < 2; ++s)
            #pragma unroll
            for (int nb = 0; nb < 4; ++nb)
                #pragma unroll
                for (int r = 0; r < 4; ++r)
                    pa[s][nb][r] = (_Float16)__builtin_amdgcn_exp2f(st[s][nb][r]);

        // PV + row-sum, K=32 frags: A = concat of pa pair (keys permuted
        // identically in A and B -> dot product unchanged)
        __builtin_amdgcn_s_setprio(1);
        #pragma unroll
        for (int s = 0; s < 2; ++s)
            #pragma unroll
            for (int a = 0; a < 2; ++a) {
                const half8 pf = __builtin_shufflevector(
                    pa[s][2 * a], pa[s][2 * a + 1], 0, 1, 2, 3, 4, 5, 6, 7);
                osum[s] = __builtin_amdgcn_mfma_f32_16x16x32_f16(pf, ones8, osum[s], 0, 0, 0);
                #pragma unroll
                for (int db = 0; db < 4; ++db)
                    o[s][db] = __builtin_amdgcn_mfma_f32_16x16x32_f16(
                        pf, vb8[a][db], o[s][db], 0, 0, 0);
            }
        __builtin_amdgcn_s_setprio(0);

        #pragma unroll
        for (int hf = 0; hf < 2; ++hf) {
            const int row = srow + 32 * hf;
            *(uint4*)(&Ks[cur ^ 1][row][scol]) = kstg[hf];
            const uint4 vv = vstg[hf];
            *(uint2*)(&Vs[cur ^ 1][row][vc0])      = make_uint2(vv.x, vv.y);
            *(uint2*)(&Vs[cur ^ 1][row][vc0 + 16]) = make_uint2(vv.z, vv.w);
        }
        __syncthreads();
    }

    // epilogue: osum[s][r] already holds the full row-sum for q=quad*4+r
    float* op = out + (size_t)bI * Sc * HIDc + h * Dc;
    #pragma unroll
    for (int s = 0; s < 2; ++s)
        #pragma unroll
        for (int r = 0; r < 4; ++r) {
            const float inv = __builtin_amdgcn_rcpf(osum[s][r]);
            const int q = qrow + 16 * s + quad * 4 + r;
            #pragma unroll
            for (int db = 0; db < 4; ++db)
                op[(size_t)q * HIDc + db * 16 + l16] = o[s][db][r] * inv;
        }
}

// ---------------------------------------------------------------------------
extern "C" void kernel_launch(void* const* d_in, const int* in_sizes, int n_in,
                              void* d_out, int out_size, void* d_ws, size_t ws_size,
                              hipStream_t stream) {
    const float* x    = (const float*)d_in[0];
    const int*   mask = (const int*)  d_in[1];
    const float* Wq   = (const float*)d_in[2];
    const float* bq   = (const float*)d_in[3];
    const float* Wk   = (const float*)d_in[4];
    const float* bk   = (const float*)d_in[5];
    const float* Wv   = (const float*)d_in[6];
    const float* bv   = (const float*)d_in[7];
    float* out = (float*)d_out;

    // workspace (f16): xh 8MB | Wt 6MB | qw 8MB | kw 8MB | vt 8MB = 38MB
    char* ws = (char*)d_ws;
    _Float16* xh = (_Float16*)(ws);
    _Float16* Wt = (_Float16*)(ws + (size_t)8  * 1024 * 1024);
    _Float16* qw = (_Float16*)(ws + (size_t)14 * 1024 * 1024);
    _Float16* kw = (_Float16*)(ws + (size_t)22 * 1024 * 1024);
    _Float16* vt = (_Float16*)(ws + (size_t)30 * 1024 * 1024);

    cvt_x_kernel<<<(Bc * Sc * HIDc) / (256 * 8), 256, 0, stream>>>(x, xh);
    cvt_w_kernel<<<dim3(HIDc / 64, HIDc / 64, 3), 256, 0, stream>>>(Wq, Wk, Wv, Wt);
    proj_kernel<<<dim3(HIDc / 128, (Bc * Sc) / 128, 3), 256, 0, stream>>>(
        xh, Wt, bq, bk, bv, qw, kw, vt);
    attn_kernel<<<dim3(Sc / 128, Bc * Hc), 256, 0, stream>>>(qw, kw, vt, mask, out);
}

// Round 8
// 161.777 us; speedup vs baseline: 1.5116x; 1.0267x over previous
//
#include <hip/hip_runtime.h>
#include <cstddef>

constexpr int Bc = 2, Sc = 2048, Hc = 16, Dc = 64, HIDc = 1024;
#define NEG_INF -10000.0f
#define LOG2E 1.44269504088896340736f

typedef _Float16 half8  __attribute__((ext_vector_type(8)));  // K=32 MFMA A/B frag
typedef _Float16 half4  __attribute__((ext_vector_type(4)));  // K=16 MFMA A/B frag
typedef __fp16   f16x2  __attribute__((ext_vector_type(2)));  // cvt_pkrtz result
typedef __fp16   f16x4  __attribute__((ext_vector_type(4)));
typedef float   floatx4 __attribute__((ext_vector_type(4)));  // MFMA C/D frag

// direct HBM -> LDS, 16B per lane, lane i lands at ldsbase + i*16
__device__ __forceinline__ void gload_lds16(const void* g, void* l) {
    __builtin_amdgcn_global_load_lds(
        (const __attribute__((address_space(1))) unsigned int*)g,
        (__attribute__((address_space(3))) unsigned int*)l, 16, 0, 0);
}

// ---------------------------------------------------------------------------
// cvt_x: x fp32 [4096][1024] -> f16 same layout. 8 elements/thread.
// ---------------------------------------------------------------------------
__global__ __launch_bounds__(256) void cvt_x_kernel(const float* __restrict__ x,
                                                    _Float16* __restrict__ xh) {
    int i = (blockIdx.x * 256 + threadIdx.x) * 8;
    float4 a = *(const float4*)(x + i);
    float4 b = *(const float4*)(x + i + 4);
    half8 h;
    h[0] = (_Float16)a.x; h[1] = (_Float16)a.y; h[2] = (_Float16)a.z; h[3] = (_Float16)a.w;
    h[4] = (_Float16)b.x; h[5] = (_Float16)b.y; h[6] = (_Float16)b.z; h[7] = (_Float16)b.w;
    *(half8*)(xh + i) = h;
}

// ---------------------------------------------------------------------------
// cvt_w: W fp32 [k][n] -> Wt f16 [n][k] (transposed), per z in {q,k,v}.
// ---------------------------------------------------------------------------
__global__ __launch_bounds__(256) void cvt_w_kernel(const float* __restrict__ Wq,
                                                    const float* __restrict__ Wk,
                                                    const float* __restrict__ Wv,
                                                    _Float16* __restrict__ Wt) {
    const float* W = (blockIdx.z == 0) ? Wq : (blockIdx.z == 1) ? Wk : Wv;
    _Float16* out = Wt + (size_t)blockIdx.z * HIDc * HIDc;
    __shared__ _Float16 T[64][65];
    const int t = threadIdx.x;
    const int kb = blockIdx.x * 64, nb = blockIdx.y * 64;
    const int r = t >> 2, c4 = (t & 3) * 16;
    #pragma unroll
    for (int i = 0; i < 16; i += 4) {
        float4 a = *(const float4*)(W + (size_t)(kb + r) * HIDc + nb + c4 + i);
        T[c4 + i + 0][r] = (_Float16)a.x;
        T[c4 + i + 1][r] = (_Float16)a.y;
        T[c4 + i + 2][r] = (_Float16)a.z;
        T[c4 + i + 3][r] = (_Float16)a.w;
    }
    __syncthreads();
    const int n = t >> 2, k4 = (t & 3) * 16;
    half8 o0, o1;
    #pragma unroll
    for (int j = 0; j < 8; ++j) { o0[j] = T[n][k4 + j]; o1[j] = T[n][k4 + 8 + j]; }
    *(half8*)(out + (size_t)(nb + n) * HIDc + kb + k4)     = o0;
    *(half8*)(out + (size_t)(nb + n) * HIDc + kb + k4 + 8) = o1;
}

// ---------------------------------------------------------------------------
// proj R18: byte-identical to R12 (m97-structure, passing).
// ---------------------------------------------------------------------------
__global__ __launch_bounds__(256, 3) void proj_kernel(
    const _Float16* __restrict__ xh, const _Float16* __restrict__ Wt,
    const float* __restrict__ bq, const float* __restrict__ bk, const float* __restrict__ bv,
    _Float16* __restrict__ qw, _Float16* __restrict__ kw, _Float16* __restrict__ vt)
{
    const int z = blockIdx.z;
    const _Float16* Wz = Wt + (size_t)z * HIDc * HIDc;
    const float* bias = (z == 0) ? bq : (z == 1) ? bk : bv;

    __shared__ __align__(16) _Float16 SM[2][2][128 * 32];

    const int t = threadIdx.x;
    const int lane = t & 63, w = t >> 6;
    const int quad = lane >> 4, l16 = lane & 15;
    const int m0 = blockIdx.y * 128, n0 = blockIdx.x * 128;
    const int wm = (w >> 1) * 64, wn = (w & 1) * 64;

    const int srl = lane >> 2;                       // row in 16-row chunk
    const int ssl = (lane & 3) ^ ((lane >> 3) & 3);  // pre-swizzled src slot

    floatx4 acc[4][4];
    #pragma unroll
    for (int mb = 0; mb < 4; ++mb)
        #pragma unroll
        for (int nb = 0; nb < 4; ++nb) acc[mb][nb] = floatx4{0.f, 0.f, 0.f, 0.f};

    auto stage = [&](int buf, int kt) {   // kt in halves
        #pragma unroll
        for (int j = 0; j < 2; ++j) {
            const int rb = (w + 4 * j) * 16;   // wave-uniform row base
            gload_lds16(xh + (size_t)(m0 + rb + srl) * HIDc + kt + ssl * 8,
                        &SM[buf][0][rb * 32]);
            gload_lds16(Wz + (size_t)(n0 + rb + srl) * HIDc + kt + ssl * 8,
                        &SM[buf][1][rb * 32]);
        }
    };

    stage(0, 0);
    __syncthreads();

    const int sA = (quad ^ ((l16 >> 1) & 3)) * 8;

    #pragma unroll 2
    for (int it = 0; it < HIDc / 32; ++it) {
        const int cur = it & 1;
        const int kn = (it + 1 < HIDc / 32) ? (it + 1) * 32 : 0;
        stage(cur ^ 1, kn);

        half8 af[4], bf[4];
        #pragma unroll
        for (int mb = 0; mb < 4; ++mb)
            af[mb] = *(const half8*)(&SM[cur][0][(wm + mb * 16 + l16) * 32 + sA]);
        #pragma unroll
        for (int nb = 0; nb < 4; ++nb)
            bf[nb] = *(const half8*)(&SM[cur][1][(wn + nb * 16 + l16) * 32 + sA]);
        #pragma unroll
        for (int mb = 0; mb < 4; ++mb)
            #pragma unroll
            for (int nb = 0; nb < 4; ++nb)
                acc[mb][nb] = __builtin_amdgcn_mfma_f32_16x16x32_f16(
                    af[mb], bf[nb], acc[mb][nb], 0, 0, 0);
        __syncthreads();
    }

    if (z == 2) {
        _Float16* T = (_Float16*)SM;     // 64 x 136 halves
        const int bI0 = m0 >> 11, m0s = m0 & (Sc - 1);
        #pragma unroll
        for (int p = 0; p < 2; ++p) {
            __syncthreads();
            if ((w & 1) == p) {
                #pragma unroll
                for (int nb = 0; nb < 4; ++nb) {
                    const int n = nb * 16 + l16;
                    const float bi = bias[n0 + p * 64 + n];
                    #pragma unroll
                    for (int mb = 0; mb < 4; ++mb) {
                        half4 h4;
                        #pragma unroll
                        for (int r = 0; r < 4; ++r)
                            h4[r] = (_Float16)(acc[mb][nb][r] + bi);
                        *(half4*)(T + n * 136 + wm + mb * 16 + quad * 4) = h4;
                    }
                }
            }
            __syncthreads();
            const int n = t >> 2;
            const int N = n0 + p * 64 + n, hh = N >> 6, d = N & 63;
            _Float16* vrow = vt + (((size_t)(bI0 * Hc + hh)) * Dc + d) * Sc + m0s;
            #pragma unroll
            for (int j = 0; j < 4; ++j) {
                const int c = (t & 3) * 32 + j * 8;
                *(uint4*)(vrow + c) = *(const uint4*)(T + n * 136 + c);
            }
        }
        return;
    }
    #pragma unroll
    for (int nb = 0; nb < 4; ++nb) {
        const int N = n0 + wn + nb * 16 + l16;
        const float bi = bias[N];
        const int h = N >> 6, d = N & 63;
        #pragma unroll
        for (int mb = 0; mb < 4; ++mb) {
            #pragma unroll
            for (int r = 0; r < 4; ++r) {
                const int M = m0 + wm + mb * 16 + quad * 4 + r;
                const int bI = M >> 11, s = M & (Sc - 1);
                const float v = acc[mb][nb][r] + bi;
                if (z == 0)
                    qw[(((size_t)(bI * Hc + h)) * Sc + s) * Dc + d] =
                        (_Float16)(v * (0.125f * LOG2E));
                else
                    kw[(((size_t)(bI * Hc + h)) * Sc + s) * Dc + d] = (_Float16)v;
            }
        }
    }
}

// ---------------------------------------------------------------------------
// attn R18 (= R17 with the cvt_pkrtz type fix): R16 math (K=32 PV, adder-as-
// C-init, ones-rowsum) plus:
//  1. XCD-grouped block remap: all 16 q-blocks of one (b,h) share flat%8 ->
//     same XCD -> that head's 512KB K/V stays L2-resident.
//  2. T15 delayed-PV pipeline: per iter, QK(t) -> PV(t-1) -> exp(t); exp's
//     VALU overlaps PV's MFMA. Named A/B reg states (no runtime indexing).
//  3. v_cvt_pkrtz packed f32->f16 for P via __fp16 vectors + bit_cast.
// ---------------------------------------------------------------------------
#define ATTN_STEP(IT, CUR, VBOUT, PAOUT, VBIN, PAIN, DOPV) do {               \
    const int kt_ = (IT) * 64;                                                \
    const int ktn_ = ((IT) + 1 < Sc / 64) ? kt_ + 64 : 0;                     \
    uint4 kstg_[2], vstg_[2];                                                 \
    _Pragma("unroll")                                                         \
    for (int hf = 0; hf < 2; ++hf) {                                          \
        const int row = srow + 32 * hf;                                       \
        kstg_[hf] = *(const uint4*)(Kp + (size_t)(ktn_ + row) * Dc + scol);   \
        vstg_[hf] = *(const uint4*)(Vp + (size_t)row * Sc + ktn_ + scol);     \
    }                                                                         \
    half8 kb_[4][2];                                                          \
    _Pragma("unroll")                                                         \
    for (int nb = 0; nb < 4; ++nb)                                            \
        _Pragma("unroll")                                                     \
        for (int hh = 0; hh < 2; ++hh)                                        \
            kb_[nb][hh] = *(const half8*)(&Ks[CUR][nb * 16 + l16][hh * 32 + quad * 8]); \
    _Pragma("unroll")                                                         \
    for (int db = 0; db < 4; ++db)                                            \
        _Pragma("unroll")                                                     \
        for (int a = 0; a < 2; ++a)                                           \
            VBOUT[a][db] = *(const half8*)(&Vs[CUR][db * 16 + l16][quad * 16 + a * 8]); \
    floatx4 st_[2][4];                                                        \
    __builtin_amdgcn_s_setprio(1);                                            \
    _Pragma("unroll")                                                         \
    for (int nb = 0; nb < 4; ++nb) {                                          \
        const floatx4 adv = *(const floatx4*)(&adder[kt_ + nb * 16 + quad * 4]); \
        _Pragma("unroll")                                                     \
        for (int s = 0; s < 2; ++s) {                                         \
            floatx4 x0 = __builtin_amdgcn_mfma_f32_16x16x32_f16(kb_[nb][0], aq[s][0], adv, 0, 0, 0); \
            st_[s][nb] = __builtin_amdgcn_mfma_f32_16x16x32_f16(kb_[nb][1], aq[s][1], x0, 0, 0, 0);  \
        }                                                                     \
    }                                                                         \
    if (DOPV) {                                                               \
        _Pragma("unroll")                                                     \
        for (int s = 0; s < 2; ++s)                                           \
            _Pragma("unroll")                                                 \
            for (int a = 0; a < 2; ++a) {                                     \
                const half8 pf = __builtin_shufflevector(                     \
                    PAIN[s][2 * a], PAIN[s][2 * a + 1], 0, 1, 2, 3, 4, 5, 6, 7); \
                osum[s] = __builtin_amdgcn_mfma_f32_16x16x32_f16(pf, ones8, osum[s], 0, 0, 0); \
                _Pragma("unroll")                                             \
                for (int db = 0; db < 4; ++db)                                \
                    o[s][db] = __builtin_amdgcn_mfma_f32_16x16x32_f16(        \
                        pf, VBIN[a][db], o[s][db], 0, 0, 0);                  \
            }                                                                 \
    }                                                                         \
    __builtin_amdgcn_s_setprio(0);                                            \
    _Pragma("unroll")                                                         \
    for (int s = 0; s < 2; ++s)                                               \
        _Pragma("unroll")                                                     \
        for (int nb = 0; nb < 4; ++nb) {                                      \
            const f16x2 lo_ = __builtin_amdgcn_cvt_pkrtz(                     \
                __builtin_amdgcn_exp2f(st_[s][nb][0]),                        \
                __builtin_amdgcn_exp2f(st_[s][nb][1]));                       \
            const f16x2 hi_ = __builtin_amdgcn_cvt_pkrtz(                     \
                __builtin_amdgcn_exp2f(st_[s][nb][2]),                        \
                __builtin_amdgcn_exp2f(st_[s][nb][3]));                       \
            const f16x4 pk_ = __builtin_shufflevector(lo_, hi_, 0, 1, 2, 3);  \
            PAOUT[s][nb] = __builtin_bit_cast(half4, pk_);                    \
        }                                                                     \
    _Pragma("unroll")                                                         \
    for (int hf = 0; hf < 2; ++hf) {                                          \
        const int row = srow + 32 * hf;                                       \
        *(uint4*)(&Ks[(CUR) ^ 1][row][scol]) = kstg_[hf];                     \
        const uint4 vv = vstg_[hf];                                           \
        *(uint2*)(&Vs[(CUR) ^ 1][row][vc0])      = make_uint2(vv.x, vv.y);    \
        *(uint2*)(&Vs[(CUR) ^ 1][row][vc0 + 16]) = make_uint2(vv.z, vv.w);    \
    }                                                                         \
    __syncthreads();                                                          \
} while (0)

__global__ __launch_bounds__(256, 2) void attn_kernel(
    const _Float16* __restrict__ qw, const _Float16* __restrict__ kw,
    const _Float16* __restrict__ vt, const int* __restrict__ mask,
    float* __restrict__ out)
{
    __shared__ __align__(16) float adder[Sc];           // 8 KB (pre-scaled log2e)
    __shared__ __align__(16) _Float16 Ks[2][64][72];    // 18 KB  [key][d]
    __shared__ __align__(16) _Float16 Vs[2][64][72];    // 18 KB  [d][key-permuted]

    const int t = threadIdx.x;
    const int lane = t & 63, w = t >> 6;
    const int quad = lane >> 4, l16 = lane & 15;

    // XCD-grouped remap: flat%8 (the XCD round-robin key) is constant per bh
    const int flat = blockIdx.y * 16 + blockIdx.x;      // 0..511, x-major
    const int idx = flat >> 3;
    const int bh = (flat & 7) * 4 + (idx & 3);          // 0..31
    const int qt = idx >> 2;                            // 0..15
    const int bI = bh >> 4, h = bh & 15;

    const _Float16* Qp = qw + (size_t)bh * Sc * Dc;
    const _Float16* Kp = kw + (size_t)bh * Sc * Dc;
    const _Float16* Vp = vt + (size_t)bh * Dc * Sc;

    const int srow = t >> 3;            // 0..31
    const int scol = (t & 7) * 8;       // elem offset, 16 B per thread
    const int m7 = t & 7;
    const int vc0 = 32 * (m7 & 1) + 4 * (m7 >> 1);   // permuted V col base

    {   // mask -> additive adder in LDS, pre-scaled by log2e
        const int4* mp = (const int4*)(mask + bI * Sc);
        #pragma unroll
        for (int i = 0; i < 2; ++i) {
            int4 m4 = mp[t * 2 + i];
            int base = (t * 2 + i) * 4;
            adder[base + 0] = (1.0f - (float)m4.x) * (NEG_INF * LOG2E);
            adder[base + 1] = (1.0f - (float)m4.y) * (NEG_INF * LOG2E);
            adder[base + 2] = (1.0f - (float)m4.z) * (NEG_INF * LOG2E);
            adder[base + 3] = (1.0f - (float)m4.w) * (NEG_INF * LOG2E);
        }
    }
    // preload tile 0 into buffer 0 (V columns permuted)
    #pragma unroll
    for (int hf = 0; hf < 2; ++hf) {
        const int row = srow + 32 * hf;
        uint4 kv = *(const uint4*)(Kp + (size_t)row * Dc + scol);
        uint4 vv = *(const uint4*)(Vp + (size_t)row * Sc + scol);
        *(uint4*)(&Ks[0][row][scol]) = kv;
        *(uint2*)(&Vs[0][row][vc0])      = make_uint2(vv.x, vv.y);
        *(uint2*)(&Vs[0][row][vc0 + 16]) = make_uint2(vv.z, vv.w);
    }

    const int qrow = qt * 128 + w * 32;
    half8 aq[2][2];
    #pragma unroll
    for (int s = 0; s < 2; ++s)
        #pragma unroll
        for (int hh = 0; hh < 2; ++hh)
            aq[s][hh] = *(const half8*)(Qp + (size_t)(qrow + 16 * s + l16) * Dc
                                        + hh * 32 + quad * 8);

    floatx4 o[2][4], osum[2];
    #pragma unroll
    for (int s = 0; s < 2; ++s) {
        osum[s] = floatx4{0.f, 0.f, 0.f, 0.f};
        #pragma unroll
        for (int db = 0; db < 4; ++db) o[s][db] = floatx4{0.f, 0.f, 0.f, 0.f};
    }
    const half8 ones8 = {(_Float16)1.f, (_Float16)1.f, (_Float16)1.f, (_Float16)1.f,
                         (_Float16)1.f, (_Float16)1.f, (_Float16)1.f, (_Float16)1.f};

    half8 vbA[2][4], vbB[2][4];
    half4 paA[2][4], paB[2][4];

    __syncthreads();   // adder + tile 0 visible

    ATTN_STEP(0, 0, vbA, paA, vbB, paB, 0);
    for (int j = 0; j < 15; ++j) {
        const int itb = 2 * j;
        ATTN_STEP(itb + 1, 1, vbB, paB, vbA, paA, 1);
        ATTN_STEP(itb + 2, 0, vbA, paA, vbB, paB, 1);
    }
    ATTN_STEP(31, 1, vbB, paB, vbA, paA, 1);

    // epilogue PV for tile 31 (held in B states)
    __builtin_amdgcn_s_setprio(1);
    #pragma unroll
    for (int s = 0; s < 2; ++s)
        #pragma unroll
        for (int a = 0; a < 2; ++a) {
            const half8 pf = __builtin_shufflevector(
                paB[s][2 * a], paB[s][2 * a + 1], 0, 1, 2, 3, 4, 5, 6, 7);
            osum[s] = __builtin_amdgcn_mfma_f32_16x16x32_f16(pf, ones8, osum[s], 0, 0, 0);
            #pragma unroll
            for (int db = 0; db < 4; ++db)
                o[s][db] = __builtin_amdgcn_mfma_f32_16x16x32_f16(
                    pf, vbB[a][db], o[s][db], 0, 0, 0);
        }
    __builtin_amdgcn_s_setprio(0);

    // epilogue: osum[s][r] holds the full row-sum for q=quad*4+r
    float* op = out + (size_t)bI * Sc * HIDc + h * Dc;
    #pragma unroll
    for (int s = 0; s < 2; ++s)
        #pragma unroll
        for (int r = 0; r < 4; ++r) {
            const float inv = __builtin_amdgcn_rcpf(osum[s][r]);
            const int q = qrow + 16 * s + quad * 4 + r;
            #pragma unroll
            for (int db = 0; db < 4; ++db)
                op[(size_t)q * HIDc + db * 16 + l16] = o[s][db][r] * inv;
        }
}

// ---------------------------------------------------------------------------
extern "C" void kernel_launch(void* const* d_in, const int* in_sizes, int n_in,
                              void* d_out, int out_size, void* d_ws, size_t ws_size,
                              hipStream_t stream) {
    const float* x    = (const float*)d_in[0];
    const int*   mask = (const int*)  d_in[1];
    const float* Wq   = (const float*)d_in[2];
    const float* bq   = (const float*)d_in[3];
    const float* Wk   = (const float*)d_in[4];
    const float* bk   = (const float*)d_in[5];
    const float* Wv   = (const float*)d_in[6];
    const float* bv   = (const float*)d_in[7];
    float* out = (float*)d_out;

    // workspace (f16): xh 8MB | Wt 6MB | qw 8MB | kw 8MB | vt 8MB = 38MB
    char* ws = (char*)d_ws;
    _Float16* xh = (_Float16*)(ws);
    _Float16* Wt = (_Float16*)(ws + (size_t)8  * 1024 * 1024);
    _Float16* qw = (_Float16*)(ws + (size_t)14 * 1024 * 1024);
    _Float16* kw = (_Float16*)(ws + (size_t)22 * 1024 * 1024);
    _Float16* vt = (_Float16*)(ws + (size_t)30 * 1024 * 1024);

    cvt_x_kernel<<<(Bc * Sc * HIDc) / (256 * 8), 256, 0, stream>>>(x, xh);
    cvt_w_kernel<<<dim3(HIDc / 64, HIDc / 64, 3), 256, 0, stream>>>(Wq, Wk, Wv, Wt);
    proj_kernel<<<dim3(HIDc / 128, (Bc * Sc) / 128, 3), 256, 0, stream>>>(
        xh, Wt, bq, bk, bv, qw, kw, vt);
    attn_kernel<<<dim3(Sc / 128, Bc * Hc), 256, 0, stream>>>(qw, kw, vt, mask, out);
}

// Round 9
// 160.754 us; speedup vs baseline: 1.5213x; 1.0064x over previous
//
#include <hip/hip_runtime.h>
#include <cstddef>

constexpr int Bc = 2, Sc = 2048, Hc = 16, Dc = 64, HIDc = 1024;
#define NEG_INF -10000.0f
#define LOG2E 1.44269504088896340736f

typedef _Float16 half8  __attribute__((ext_vector_type(8)));  // K=32 MFMA A/B frag
typedef _Float16 half4  __attribute__((ext_vector_type(4)));  // K=16 MFMA A/B frag
typedef __fp16   f16x2  __attribute__((ext_vector_type(2)));  // cvt_pkrtz result
typedef __fp16   f16x4  __attribute__((ext_vector_type(4)));
typedef float   floatx4 __attribute__((ext_vector_type(4)));  // MFMA C/D frag

// direct HBM -> LDS, 16B per lane, lane i lands at ldsbase + i*16
__device__ __forceinline__ void gload_lds16(const void* g, void* l) {
    __builtin_amdgcn_global_load_lds(
        (const __attribute__((address_space(1))) unsigned int*)g,
        (__attribute__((address_space(3))) unsigned int*)l, 16, 0, 0);
}

// ---------------------------------------------------------------------------
// cvt_x: x fp32 [4096][1024] -> f16 same layout. 8 elements/thread.
// ---------------------------------------------------------------------------
__global__ __launch_bounds__(256) void cvt_x_kernel(const float* __restrict__ x,
                                                    _Float16* __restrict__ xh) {
    int i = (blockIdx.x * 256 + threadIdx.x) * 8;
    float4 a = *(const float4*)(x + i);
    float4 b = *(const float4*)(x + i + 4);
    half8 h;
    h[0] = (_Float16)a.x; h[1] = (_Float16)a.y; h[2] = (_Float16)a.z; h[3] = (_Float16)a.w;
    h[4] = (_Float16)b.x; h[5] = (_Float16)b.y; h[6] = (_Float16)b.z; h[7] = (_Float16)b.w;
    *(half8*)(xh + i) = h;
}

// ---------------------------------------------------------------------------
// cvt_w: W fp32 [k][n] -> Wt f16 [n][k] (transposed), per z in {q,k,v}.
// ---------------------------------------------------------------------------
__global__ __launch_bounds__(256) void cvt_w_kernel(const float* __restrict__ Wq,
                                                    const float* __restrict__ Wk,
                                                    const float* __restrict__ Wv,
                                                    _Float16* __restrict__ Wt) {
    const float* W = (blockIdx.z == 0) ? Wq : (blockIdx.z == 1) ? Wk : Wv;
    _Float16* out = Wt + (size_t)blockIdx.z * HIDc * HIDc;
    __shared__ _Float16 T[64][65];
    const int t = threadIdx.x;
    const int kb = blockIdx.x * 64, nb = blockIdx.y * 64;
    const int r = t >> 2, c4 = (t & 3) * 16;
    #pragma unroll
    for (int i = 0; i < 16; i += 4) {
        float4 a = *(const float4*)(W + (size_t)(kb + r) * HIDc + nb + c4 + i);
        T[c4 + i + 0][r] = (_Float16)a.x;
        T[c4 + i + 1][r] = (_Float16)a.y;
        T[c4 + i + 2][r] = (_Float16)a.z;
        T[c4 + i + 3][r] = (_Float16)a.w;
    }
    __syncthreads();
    const int n = t >> 2, k4 = (t & 3) * 16;
    half8 o0, o1;
    #pragma unroll
    for (int j = 0; j < 8; ++j) { o0[j] = T[n][k4 + j]; o1[j] = T[n][k4 + 8 + j]; }
    *(half8*)(out + (size_t)(nb + n) * HIDc + kb + k4)     = o0;
    *(half8*)(out + (size_t)(nb + n) * HIDc + kb + k4 + 8) = o1;
}

// ---------------------------------------------------------------------------
// proj R19: byte-identical to R12 (m97-structure, passing).
// ---------------------------------------------------------------------------
__global__ __launch_bounds__(256, 3) void proj_kernel(
    const _Float16* __restrict__ xh, const _Float16* __restrict__ Wt,
    const float* __restrict__ bq, const float* __restrict__ bk, const float* __restrict__ bv,
    _Float16* __restrict__ qw, _Float16* __restrict__ kw, _Float16* __restrict__ vt)
{
    const int z = blockIdx.z;
    const _Float16* Wz = Wt + (size_t)z * HIDc * HIDc;
    const float* bias = (z == 0) ? bq : (z == 1) ? bk : bv;

    __shared__ __align__(16) _Float16 SM[2][2][128 * 32];

    const int t = threadIdx.x;
    const int lane = t & 63, w = t >> 6;
    const int quad = lane >> 4, l16 = lane & 15;
    const int m0 = blockIdx.y * 128, n0 = blockIdx.x * 128;
    const int wm = (w >> 1) * 64, wn = (w & 1) * 64;

    const int srl = lane >> 2;                       // row in 16-row chunk
    const int ssl = (lane & 3) ^ ((lane >> 3) & 3);  // pre-swizzled src slot

    floatx4 acc[4][4];
    #pragma unroll
    for (int mb = 0; mb < 4; ++mb)
        #pragma unroll
        for (int nb = 0; nb < 4; ++nb) acc[mb][nb] = floatx4{0.f, 0.f, 0.f, 0.f};

    auto stage = [&](int buf, int kt) {   // kt in halves
        #pragma unroll
        for (int j = 0; j < 2; ++j) {
            const int rb = (w + 4 * j) * 16;   // wave-uniform row base
            gload_lds16(xh + (size_t)(m0 + rb + srl) * HIDc + kt + ssl * 8,
                        &SM[buf][0][rb * 32]);
            gload_lds16(Wz + (size_t)(n0 + rb + srl) * HIDc + kt + ssl * 8,
                        &SM[buf][1][rb * 32]);
        }
    };

    stage(0, 0);
    __syncthreads();

    const int sA = (quad ^ ((l16 >> 1) & 3)) * 8;

    #pragma unroll 2
    for (int it = 0; it < HIDc / 32; ++it) {
        const int cur = it & 1;
        const int kn = (it + 1 < HIDc / 32) ? (it + 1) * 32 : 0;
        stage(cur ^ 1, kn);

        half8 af[4], bf[4];
        #pragma unroll
        for (int mb = 0; mb < 4; ++mb)
            af[mb] = *(const half8*)(&SM[cur][0][(wm + mb * 16 + l16) * 32 + sA]);
        #pragma unroll
        for (int nb = 0; nb < 4; ++nb)
            bf[nb] = *(const half8*)(&SM[cur][1][(wn + nb * 16 + l16) * 32 + sA]);
        #pragma unroll
        for (int mb = 0; mb < 4; ++mb)
            #pragma unroll
            for (int nb = 0; nb < 4; ++nb)
                acc[mb][nb] = __builtin_amdgcn_mfma_f32_16x16x32_f16(
                    af[mb], bf[nb], acc[mb][nb], 0, 0, 0);
        __syncthreads();
    }

    if (z == 2) {
        _Float16* T = (_Float16*)SM;     // 64 x 136 halves
        const int bI0 = m0 >> 11, m0s = m0 & (Sc - 1);
        #pragma unroll
        for (int p = 0; p < 2; ++p) {
            __syncthreads();
            if ((w & 1) == p) {
                #pragma unroll
                for (int nb = 0; nb < 4; ++nb) {
                    const int n = nb * 16 + l16;
                    const float bi = bias[n0 + p * 64 + n];
                    #pragma unroll
                    for (int mb = 0; mb < 4; ++mb) {
                        half4 h4;
                        #pragma unroll
                        for (int r = 0; r < 4; ++r)
                            h4[r] = (_Float16)(acc[mb][nb][r] + bi);
                        *(half4*)(T + n * 136 + wm + mb * 16 + quad * 4) = h4;
                    }
                }
            }
            __syncthreads();
            const int n = t >> 2;
            const int N = n0 + p * 64 + n, hh = N >> 6, d = N & 63;
            _Float16* vrow = vt + (((size_t)(bI0 * Hc + hh)) * Dc + d) * Sc + m0s;
            #pragma unroll
            for (int j = 0; j < 4; ++j) {
                const int c = (t & 3) * 32 + j * 8;
                *(uint4*)(vrow + c) = *(const uint4*)(T + n * 136 + c);
            }
        }
        return;
    }
    #pragma unroll
    for (int nb = 0; nb < 4; ++nb) {
        const int N = n0 + wn + nb * 16 + l16;
        const float bi = bias[N];
        const int h = N >> 6, d = N & 63;
        #pragma unroll
        for (int mb = 0; mb < 4; ++mb) {
            #pragma unroll
            for (int r = 0; r < 4; ++r) {
                const int M = m0 + wm + mb * 16 + quad * 4 + r;
                const int bI = M >> 11, s = M & (Sc - 1);
                const float v = acc[mb][nb][r] + bi;
                if (z == 0)
                    qw[(((size_t)(bI * Hc + h)) * Sc + s) * Dc + d] =
                        (_Float16)(v * (0.125f * LOG2E));
                else
                    kw[(((size_t)(bI * Hc + h)) * Sc + s) * Dc + d] = (_Float16)v;
            }
        }
    }
}

// ---------------------------------------------------------------------------
// attn R19 (= R18 + conflict-free LDS):
// Ks/Vs rows shrink 72 -> 64 halves (128B) and the 16B slot index is
// XOR-swizzled with (row&7) on BOTH write and read sides. The old 144B row
// stride put all 64 lanes of every frag read on banks = 0 mod 4 (8-way
// conflict, the 5.3M counter). With slot^(row&7): reads hit 8 dwords/bank
// exactly (conflict-free); K staging writes and V's 8B-granular permuted
// writes (each uint2 inside one 16B slot) also conflict-free.
// LDS 45056 -> 40960 B: up to 4 blocks/CU can now co-reside.
// ---------------------------------------------------------------------------
#define ATTN_STEP(IT, CUR, VBOUT, PAOUT, VBIN, PAIN, DOPV) do {               \
    const int kt_ = (IT) * 64;                                                \
    const int ktn_ = ((IT) + 1 < Sc / 64) ? kt_ + 64 : 0;                     \
    uint4 kstg_[2], vstg_[2];                                                 \
    _Pragma("unroll")                                                         \
    for (int hf = 0; hf < 2; ++hf) {                                          \
        const int row = srow + 32 * hf;                                       \
        kstg_[hf] = *(const uint4*)(Kp + (size_t)(ktn_ + row) * Dc + scol);   \
        vstg_[hf] = *(const uint4*)(Vp + (size_t)row * Sc + ktn_ + scol);     \
    }                                                                         \
    half8 kb_[4][2];                                                          \
    _Pragma("unroll")                                                         \
    for (int nb = 0; nb < 4; ++nb)                                            \
        _Pragma("unroll")                                                     \
        for (int hh = 0; hh < 2; ++hh)                                        \
            kb_[nb][hh] = *(const half8*)(                                    \
                &Ks[CUR][nb * 16 + l16][((hh * 4 + quad) ^ swz) * 8]);        \
    _Pragma("unroll")                                                         \
    for (int db = 0; db < 4; ++db)                                            \
        _Pragma("unroll")                                                     \
        for (int a = 0; a < 2; ++a)                                           \
            VBOUT[a][db] = *(const half8*)(                                   \
                &Vs[CUR][db * 16 + l16][((quad * 2 + a) ^ swz) * 8]);         \
    floatx4 st_[2][4];                                                        \
    __builtin_amdgcn_s_setprio(1);                                            \
    _Pragma("unroll")                                                         \
    for (int nb = 0; nb < 4; ++nb) {                                          \
        const floatx4 adv = *(const floatx4*)(&adder[kt_ + nb * 16 + quad * 4]); \
        _Pragma("unroll")                                                     \
        for (int s = 0; s < 2; ++s) {                                         \
            floatx4 x0 = __builtin_amdgcn_mfma_f32_16x16x32_f16(kb_[nb][0], aq[s][0], adv, 0, 0, 0); \
            st_[s][nb] = __builtin_amdgcn_mfma_f32_16x16x32_f16(kb_[nb][1], aq[s][1], x0, 0, 0, 0);  \
        }                                                                     \
    }                                                                         \
    if (DOPV) {                                                               \
        _Pragma("unroll")                                                     \
        for (int s = 0; s < 2; ++s)                                           \
            _Pragma("unroll")                                                 \
            for (int a = 0; a < 2; ++a) {                                     \
                const half8 pf = __builtin_shufflevector(                     \
                    PAIN[s][2 * a], PAIN[s][2 * a + 1], 0, 1, 2, 3, 4, 5, 6, 7); \
                osum[s] = __builtin_amdgcn_mfma_f32_16x16x32_f16(pf, ones8, osum[s], 0, 0, 0); \
                _Pragma("unroll")                                             \
                for (int db = 0; db < 4; ++db)                                \
                    o[s][db] = __builtin_amdgcn_mfma_f32_16x16x32_f16(        \
                        pf, VBIN[a][db], o[s][db], 0, 0, 0);                  \
            }                                                                 \
    }                                                                         \
    __builtin_amdgcn_s_setprio(0);                                            \
    _Pragma("unroll")                                                         \
    for (int s = 0; s < 2; ++s)                                               \
        _Pragma("unroll")                                                     \
        for (int nb = 0; nb < 4; ++nb) {                                      \
            const f16x2 lo_ = __builtin_amdgcn_cvt_pkrtz(                     \
                __builtin_amdgcn_exp2f(st_[s][nb][0]),                        \
                __builtin_amdgcn_exp2f(st_[s][nb][1]));                       \
            const f16x2 hi_ = __builtin_amdgcn_cvt_pkrtz(                     \
                __builtin_amdgcn_exp2f(st_[s][nb][2]),                        \
                __builtin_amdgcn_exp2f(st_[s][nb][3]));                       \
            const f16x4 pk_ = __builtin_shufflevector(lo_, hi_, 0, 1, 2, 3);  \
            PAOUT[s][nb] = __builtin_bit_cast(half4, pk_);                    \
        }                                                                     \
    _Pragma("unroll")                                                         \
    for (int hf = 0; hf < 2; ++hf) {                                          \
        const int row = srow + 32 * hf;                                       \
        const int rs = row & 7;                                               \
        *(uint4*)(&Ks[(CUR) ^ 1][row][(m7 ^ rs) * 8]) = kstg_[hf];            \
        const uint4 vv = vstg_[hf];                                           \
        *(uint2*)(&Vs[(CUR) ^ 1][row][(vs0 ^ rs) * 8 + vio])       = make_uint2(vv.x, vv.y); \
        *(uint2*)(&Vs[(CUR) ^ 1][row][((vs0 + 2) ^ rs) * 8 + vio]) = make_uint2(vv.z, vv.w); \
    }                                                                         \
    __syncthreads();                                                          \
} while (0)

__global__ __launch_bounds__(256, 2) void attn_kernel(
    const _Float16* __restrict__ qw, const _Float16* __restrict__ kw,
    const _Float16* __restrict__ vt, const int* __restrict__ mask,
    float* __restrict__ out)
{
    __shared__ __align__(16) float adder[Sc];           // 8 KB (pre-scaled log2e)
    __shared__ __align__(16) _Float16 Ks[2][64][64];    // 16 KB  [key][d] swizzled
    __shared__ __align__(16) _Float16 Vs[2][64][64];    // 16 KB  [d][key-perm] swizzled

    const int t = threadIdx.x;
    const int lane = t & 63, w = t >> 6;
    const int quad = lane >> 4, l16 = lane & 15;
    const int swz = l16 & 7;

    // XCD-grouped remap: flat%8 (the XCD round-robin key) is constant per bh
    const int flat = blockIdx.y * 16 + blockIdx.x;      // 0..511, x-major
    const int idx = flat >> 3;
    const int bh = (flat & 7) * 4 + (idx & 3);          // 0..31
    const int qt = idx >> 2;                            // 0..15
    const int bI = bh >> 4, h = bh & 15;

    const _Float16* Qp = qw + (size_t)bh * Sc * Dc;
    const _Float16* Kp = kw + (size_t)bh * Sc * Dc;
    const _Float16* Vp = vt + (size_t)bh * Dc * Sc;

    const int srow = t >> 3;            // 0..31
    const int scol = (t & 7) * 8;       // elem offset, 16 B per thread
    const int m7 = t & 7;
    const int vs0 = 4 * (m7 & 1) + (m7 >> 2);   // V slot of first uint2
    const int vio = (m7 & 2) * 2;               // intra-slot half offset

    {   // mask -> additive adder in LDS, pre-scaled by log2e
        const int4* mp = (const int4*)(mask + bI * Sc);
        #pragma unroll
        for (int i = 0; i < 2; ++i) {
            int4 m4 = mp[t * 2 + i];
            int base = (t * 2 + i) * 4;
            adder[base + 0] = (1.0f - (float)m4.x) * (NEG_INF * LOG2E);
            adder[base + 1] = (1.0f - (float)m4.y) * (NEG_INF * LOG2E);
            adder[base + 2] = (1.0f - (float)m4.z) * (NEG_INF * LOG2E);
            adder[base + 3] = (1.0f - (float)m4.w) * (NEG_INF * LOG2E);
        }
    }
    // preload tile 0 into buffer 0 (swizzled slots)
    #pragma unroll
    for (int hf = 0; hf < 2; ++hf) {
        const int row = srow + 32 * hf;
        const int rs = row & 7;
        uint4 kv = *(const uint4*)(Kp + (size_t)row * Dc + scol);
        uint4 vv = *(const uint4*)(Vp + (size_t)row * Sc + scol);
        *(uint4*)(&Ks[0][row][(m7 ^ rs) * 8]) = kv;
        *(uint2*)(&Vs[0][row][(vs0 ^ rs) * 8 + vio])       = make_uint2(vv.x, vv.y);
        *(uint2*)(&Vs[0][row][((vs0 + 2) ^ rs) * 8 + vio]) = make_uint2(vv.z, vv.w);
    }

    const int qrow = qt * 128 + w * 32;
    half8 aq[2][2];
    #pragma unroll
    for (int s = 0; s < 2; ++s)
        #pragma unroll
        for (int hh = 0; hh < 2; ++hh)
            aq[s][hh] = *(const half8*)(Qp + (size_t)(qrow + 16 * s + l16) * Dc
                                        + hh * 32 + quad * 8);

    floatx4 o[2][4], osum[2];
    #pragma unroll
    for (int s = 0; s < 2; ++s) {
        osum[s] = floatx4{0.f, 0.f, 0.f, 0.f};
        #pragma unroll
        for (int db = 0; db < 4; ++db) o[s][db] = floatx4{0.f, 0.f, 0.f, 0.f};
    }
    const half8 ones8 = {(_Float16)1.f, (_Float16)1.f, (_Float16)1.f, (_Float16)1.f,
                         (_Float16)1.f, (_Float16)1.f, (_Float16)1.f, (_Float16)1.f};

    half8 vbA[2][4], vbB[2][4];
    half4 paA[2][4], paB[2][4];

    __syncthreads();   // adder + tile 0 visible

    ATTN_STEP(0, 0, vbA, paA, vbB, paB, 0);
    for (int j = 0; j < 15; ++j) {
        const int itb = 2 * j;
        ATTN_STEP(itb + 1, 1, vbB, paB, vbA, paA, 1);
        ATTN_STEP(itb + 2, 0, vbA, paA, vbB, paB, 1);
    }
    ATTN_STEP(31, 1, vbB, paB, vbA, paA, 1);

    // epilogue PV for tile 31 (held in B states)
    __builtin_amdgcn_s_setprio(1);
    #pragma unroll
    for (int s = 0; s < 2; ++s)
        #pragma unroll
        for (int a = 0; a < 2; ++a) {
            const half8 pf = __builtin_shufflevector(
                paB[s][2 * a], paB[s][2 * a + 1], 0, 1, 2, 3, 4, 5, 6, 7);
            osum[s] = __builtin_amdgcn_mfma_f32_16x16x32_f16(pf, ones8, osum[s], 0, 0, 0);
            #pragma unroll
            for (int db = 0; db < 4; ++db)
                o[s][db] = __builtin_amdgcn_mfma_f32_16x16x32_f16(
                    pf, vbB[a][db], o[s][db], 0, 0, 0);
        }
    __builtin_amdgcn_s_setprio(0);

    // epilogue: osum[s][r] holds the full row-sum for q=quad*4+r
    float* op = out + (size_t)bI * Sc * HIDc + h * Dc;
    #pragma unroll
    for (int s = 0; s < 2; ++s)
        #pragma unroll
        for (int r = 0; r < 4; ++r) {
            const float inv = __builtin_amdgcn_rcpf(osum[s][r]);
            const int q = qrow + 16 * s + quad * 4 + r;
            #pragma unroll
            for (int db = 0; db < 4; ++db)
                op[(size_t)q * HIDc + db * 16 + l16] = o[s][db][r] * inv;
        }
}

// ---------------------------------------------------------------------------
extern "C" void kernel_launch(void* const* d_in, const int* in_sizes, int n_in,
                              void* d_out, int out_size, void* d_ws, size_t ws_size,
                              hipStream_t stream) {
    const float* x    = (const float*)d_in[0];
    const int*   mask = (const int*)  d_in[1];
    const float* Wq   = (const float*)d_in[2];
    const float* bq   = (const float*)d_in[3];
    const float* Wk   = (const float*)d_in[4];
    const float* bk   = (const float*)d_in[5];
    const float* Wv   = (const float*)d_in[6];
    const float* bv   = (const float*)d_in[7];
    float* out = (float*)d_out;

    // workspace (f16): xh 8MB | Wt 6MB | qw 8MB | kw 8MB | vt 8MB = 38MB
    char* ws = (char*)d_ws;
    _Float16* xh = (_Float16*)(ws);
    _Float16* Wt = (_Float16*)(ws + (size_t)8  * 1024 * 1024);
    _Float16* qw = (_Float16*)(ws + (size_t)14 * 1024 * 1024);
    _Float16* kw = (_Float16*)(ws + (size_t)22 * 1024 * 1024);
    _Float16* vt = (_Float16*)(ws + (size_t)30 * 1024 * 1024);

    cvt_x_kernel<<<(Bc * Sc * HIDc) / (256 * 8), 256, 0, stream>>>(x, xh);
    cvt_w_kernel<<<dim3(HIDc / 64, HIDc / 64, 3), 256, 0, stream>>>(Wq, Wk, Wv, Wt);
    proj_kernel<<<dim3(HIDc / 128, (Bc * Sc) / 128, 3), 256, 0, stream>>>(
        xh, Wt, bq, bk, bv, qw, kw, vt);
    attn_kernel<<<dim3(Sc / 128, Bc * Hc), 256, 0, stream>>>(qw, kw, vt, mask, out);
}